// Round 8
// baseline (183.264 us; speedup 1.0000x reference)
//
#include <hip/hip_runtime.h>

// APMLSparse: B=4, N=M=4096, D=3.
// loss = sum_rows sum_{kept j} p_ij * d_ij, p = softmax_j(-d_i),
// kept = descending-p prefix until cumulative mass >= P_MIN = 0.8.
//
// R15: 2-wave-per-row pair split. Span accounting of R14: per-wave span
// ~70K cyc vs ~5K issue => waves stalled 93%; residency capped ~15
// waves/CU because p[64] spills to AGPRs (VGPR_Count=48 can't hold it;
// gfx950 unified file => ~112-128 total regs/wave). The untried lever is
// REGISTERS PER WAVE: each wave now owns 32 elements (p[32]), total
// ~64-80 regs => 25-32 waves/CU, halved chains, halved setup loads.
// Cross-wave combines via LDS + __syncthreads (block = 128 = exactly the
// pair; all loop guards use combined values => uniform => barrier-safe).
// Ping-pong parity buffers per loop make 1 barrier/round safe.
// Z/spd become (w0-half + w1-half) reassociations -- same class as the
// R12/R14 reassociations that passed with absmax 0. Selection logic
// (probe updates, C2 exact distinct-value walk, tie rule) operates on
// combined values, bit-identical in both waves.

#define MCOLS 4096
#define KW    32            // elements per lane per wave (4096 / 64 / 2)
#define P_MIN 0.8f

// ---- DPP wave64 reductions (old=0 => disabled/out-of-range lanes add 0) ----
template <int CTRL, int RM, int BM, bool BC>
__device__ __forceinline__ float dpp_mov0(float x) {
    return __int_as_float(__builtin_amdgcn_update_dpp(
        0, __float_as_int(x), CTRL, RM, BM, BC));
}
__device__ __forceinline__ float dppSum(float v) {
    v += dpp_mov0<0x111, 0xF, 0xF, true >(v);   // row_shr:1
    v += dpp_mov0<0x112, 0xF, 0xF, true >(v);   // row_shr:2
    v += dpp_mov0<0x114, 0xF, 0xF, true >(v);   // row_shr:4
    v += dpp_mov0<0x118, 0xF, 0xF, true >(v);   // row_shr:8
    v += dpp_mov0<0x142, 0xA, 0xF, false>(v);   // row_bcast15 -> rows 1,3
    v += dpp_mov0<0x143, 0xC, 0xF, false>(v);   // row_bcast31 -> rows 2,3
    return __int_as_float(__builtin_amdgcn_readlane(__float_as_int(v), 63));
}
__device__ __forceinline__ void dppSum2(float& a, float& b) {
    a += dpp_mov0<0x111, 0xF, 0xF, true >(a); b += dpp_mov0<0x111, 0xF, 0xF, true >(b);
    a += dpp_mov0<0x112, 0xF, 0xF, true >(a); b += dpp_mov0<0x112, 0xF, 0xF, true >(b);
    a += dpp_mov0<0x114, 0xF, 0xF, true >(a); b += dpp_mov0<0x114, 0xF, 0xF, true >(b);
    a += dpp_mov0<0x118, 0xF, 0xF, true >(a); b += dpp_mov0<0x118, 0xF, 0xF, true >(b);
    a += dpp_mov0<0x142, 0xA, 0xF, false>(a); b += dpp_mov0<0x142, 0xA, 0xF, false>(b);
    a += dpp_mov0<0x143, 0xC, 0xF, false>(a); b += dpp_mov0<0x143, 0xC, 0xF, false>(b);
    a = __int_as_float(__builtin_amdgcn_readlane(__float_as_int(a), 63));
    b = __int_as_float(__builtin_amdgcn_readlane(__float_as_int(b), 63));
}
__device__ __forceinline__ float dppMax(float v) {   // nonneg inputs only
    v = fmaxf(v, dpp_mov0<0x111, 0xF, 0xF, true >(v));
    v = fmaxf(v, dpp_mov0<0x112, 0xF, 0xF, true >(v));
    v = fmaxf(v, dpp_mov0<0x114, 0xF, 0xF, true >(v));
    v = fmaxf(v, dpp_mov0<0x118, 0xF, 0xF, true >(v));
    v = fmaxf(v, dpp_mov0<0x142, 0xA, 0xF, false>(v));
    v = fmaxf(v, dpp_mov0<0x143, 0xC, 0xF, false>(v));
    return __int_as_float(__builtin_amdgcn_readlane(__float_as_int(v), 63));
}

__global__ __launch_bounds__(128) void apml_row_pair(
        const float* __restrict__ x, const float* __restrict__ y,
        float* __restrict__ partial, float* __restrict__ out) {
    __shared__ __align__(16) float scomp[256];
    __shared__ float xf_set[4];        // Zw, pmw per wave
    __shared__ float xf_g[2];
    __shared__ float xf_warm[2][4];    // parity x (a0,a1 per wave)
    __shared__ float xf_a0[4];
    __shared__ int   xi_a0[4];
    __shared__ float xf_A[2][2];
    __shared__ int   xi_A[2][2];
    __shared__ int   xi_bc[2];
    __shared__ float xf_c1[2][4];
    __shared__ int   xi_c1[2][4];
    __shared__ float xf_c2v[2][2];
    __shared__ int   xi_c2c[2][2];
    __shared__ float xf_spd[2];

    const int tid  = threadIdx.x;
    const int wid  = tid >> 6;          // 0 or 1
    const int lane = tid & 63;
    const int row  = blockIdx.x;
    const int b    = row >> 12;         // row / 4096

    const float x0 = x[row * 3 + 0];
    const float x1 = x[row * 3 + 1];
    const float x2 = x[row * 3 + 2];
    const float* yb = y + (size_t)b * MCOLS * 3;

    // ---- setup: p = exp(-d); wave w owns global k2 = w*KW + k ----
    float p[KW];
    float zl = 0.0f, pm0 = 0.0f, pm1 = 0.0f;
    #pragma unroll
    for (int k = 0; k < KW; ++k) {
        const int j = (wid * KW + k) * 64 + lane;
        const float y0 = yb[j * 3 + 0];
        const float y1 = yb[j * 3 + 1];
        const float y2 = yb[j * 3 + 2];
        const float dx = x0 - y0, dy = x1 - y1, dz = x2 - y2;
        const float sq = fmaxf(dx * dx + dy * dy + dz * dz, 1e-12f); // EPS^2
        const float pk = __expf(-sqrtf(sq));
        p[k] = pk;
        zl  += pk;
        if (k & 1) pm1 = fmaxf(pm1, pk); else pm0 = fmaxf(pm0, pk);
    }
    const float Zw  = dppSum(zl);
    const float pmw = dppMax(fmaxf(pm0, pm1));
    if (lane == 0) { xf_set[wid * 2 + 0] = Zw; xf_set[wid * 2 + 1] = pmw; }
    __syncthreads();
    const float Z    = xf_set[0] + xf_set[2];
    const float pmax = fmaxf(xf_set[1], xf_set[3]);
    const float target = P_MIN * Z;
    const float pTop = __uint_as_float(__float_as_uint(pmax) + 1u);

    // ---- warm-start: 3 dual rounds, 512 samples (both waves' p[0..3]) ----
    float ssl = 0.0f, ssh = pTop;
    {
        const float gw = dppSum(p[0] + p[1] + p[2] + p[3]);
        if (lane == 0) xf_g[wid] = gw;
        __syncthreads();
        float eGl = 8.0f * (xf_g[0] + xf_g[1]);   // Ghat(0), scale 4096/512
        float eGh = 0.0f;
        for (int it = 0; it < 3; ++it) {
            const float sB = 0.5f * (ssl + ssh);
            if (!(sB > ssl && sB < ssh)) break;            // uniform
            float sA = ssl + (ssh - ssl) *
                       ((eGl - target) / fmaxf(eGl - eGh, 1e-30f));
            if (!(sA > ssl && sA < ssh)) sA = sB;
            const float t0 = fminf(sA, sB), t1 = fmaxf(sA, sB);

            float a0 = 0.0f, a1 = 0.0f;
            #pragma unroll
            for (int q = 0; q < 4; ++q) {
                a0 += (p[q] >= t0) ? p[q] : 0.0f;
                a1 += (p[q] >= t1) ? p[q] : 0.0f;
            }
            dppSum2(a0, a1);
            if (lane == 0) { xf_warm[it & 1][wid * 2 + 0] = a0;
                             xf_warm[it & 1][wid * 2 + 1] = a1; }
            __syncthreads();
            const float M0 = 8.0f * (xf_warm[it & 1][0] + xf_warm[it & 1][2]);
            const float M1 = 8.0f * (xf_warm[it & 1][1] + xf_warm[it & 1][3]);
            if      (M1 >= target) { ssl = t1; eGl = M1; }
            else if (M0 >= target) { ssl = t0; eGl = M0;
                                     ssh = t1; eGh = M1; }
            else                   { ssh = t0; eGh = M0; }
        }
    }

    // ---- Phase A0: dual-threshold exact pass at (ssl, ssh) ----
    float sl = 0.0f, sh = pTop;
    float Gl = Z,    Gh = 0.0f;
    int   Cl = MCOLS, Ch = 0;
    int   clw = KW * 64, chw = 0;       // own-wave counts at sl / sh
    {
        float ml = 0.0f, mh = 0.0f;
        int   clo = 0,   cho = 0;
        #pragma unroll
        for (int k = 0; k < KW; ++k) {
            const float pk = p[k];
            const bool gl = (pk >= ssl);
            const bool gh = (pk >= ssh);
            ml += gl ? pk : 0.0f; clo += (int)__popcll(__ballot(gl));
            mh += gh ? pk : 0.0f; cho += (int)__popcll(__ballot(gh));
        }
        dppSum2(ml, mh);
        if (lane == 0) { xf_a0[wid * 2 + 0] = ml; xf_a0[wid * 2 + 1] = mh;
                         xi_a0[wid * 2 + 0] = clo; xi_a0[wid * 2 + 1] = cho; }
        __syncthreads();
        const float MlC = xf_a0[0] + xf_a0[2];
        const float MhC = xf_a0[1] + xf_a0[3];
        const int   ClC = xi_a0[0] + xi_a0[2];
        const int   ChC = xi_a0[1] + xi_a0[3];
        if (MlC >= target) { sl = ssl; Gl = MlC; Cl = ClC; clw = clo; }
        else               { sh = ssl; Gh = MlC; Ch = ClC; chw = clo; }
        if (MhC >= target) { sl = ssh; Gl = MhC; Cl = ChC; clw = cho; }
        else if (ssh < sh) { sh = ssh; Gh = MhC; Ch = ChC; chw = cho; }
    }

    // ---- Phase A: exact probes until band <= 256 ----
    for (int it = 0; it < 10 && (Cl - Ch) > 256; ++it) {
        float s;
        if (it & 1) {
            s = 0.5f * (sl + sh);
        } else {
            const float den = fmaxf(Gl - Gh, 1e-30f);
            s = sl + (sh - sl) * ((Gl - target) / den);
        }
        if (!(s > sl && s < sh)) s = 0.5f * (sl + sh);
        if (!(s > sl && s < sh)) break;        // uniform ulp-width bracket

        float m0 = 0.0f, m1 = 0.0f;
        int   c = 0;
        #pragma unroll
        for (int k = 0; k < KW; k += 2) {
            const bool g0 = (p[k]     >= s);
            const bool g1 = (p[k + 1] >= s);
            m0 += g0 ? p[k]     : 0.0f; c += (int)__popcll(__ballot(g0));
            m1 += g1 ? p[k + 1] : 0.0f; c += (int)__popcll(__ballot(g1));
        }
        const float mw = dppSum(m0 + m1);
        if (lane == 0) { xf_A[it & 1][wid] = mw; xi_A[it & 1][wid] = c; }
        __syncthreads();
        const float m = xf_A[it & 1][0] + xf_A[it & 1][1];
        const int   cC = xi_A[it & 1][0] + xi_A[it & 1][1];
        if (m >= target) { sl = s; Gl = m; Cl = cC; clw = c; }
        else             { sh = s; Gh = m; Ch = cC; chw = c; }
    }

    // ---- Phase B: compact band [sl, sh); wave1 offsets by wave0's count ----
    const int bc_own = clw - chw;
    if (lane == 0) xi_bc[wid] = bc_own;
    __syncthreads();
    const int C    = xi_bc[0] + xi_bc[1];
    int       ofs  = (wid == 0) ? 0 : xi_bc[0];
    #pragma unroll
    for (int k = 0; k < KW; ++k) {
        const bool band = (p[k] >= sl) && (p[k] < sh);
        const unsigned long long mk = __ballot(band);
        if (band) {
            const unsigned mlo = (unsigned)mk, mhi = (unsigned)(mk >> 32);
            const int within = __builtin_amdgcn_mbcnt_hi(
                                   mhi, __builtin_amdgcn_mbcnt_lo(mlo, 0));
            const int pos = ofs + within;
            if (pos < 256) scomp[pos] = p[k];
        }
        ofs += (int)__popcll(mk);
    }
    __syncthreads();                            // cross-wave visibility
    float cp[2];
    bool  cv[2];
    #pragma unroll
    for (int q = 0; q < 2; ++q) {
        const int idx = q * 128 + wid * 64 + lane;
        cv[q] = (idx < C) && (idx < 256);
        cp[q] = cv[q] ? scomp[idx] : 0.0f;
    }

    float pstar, mb = 0.0f;
    int   cnt = 1;
    bool  haveTie;

    if (C > 256) {
        // fallback (rare): keep everything >= sl (off by boundary elems)
        pstar = (sl > 0.0f) ? __uint_as_float(__float_as_uint(sl) - 1u) : 0.0f;
        haveTie = false;
    } else {
        // ---- Phase C1: fine probes, 2 thresholds per round ----
        float lo_s = sl, hi_s = sh, lo_G = Gl, hi_G = Gh;
        int   lo_C = Cl, hi_C = Ch;
        for (int it = 0; it < 6 && (lo_C - hi_C) > 2; ++it) {
            const float sB = 0.5f * (lo_s + hi_s);
            if (!(sB > lo_s && sB < hi_s)) break;   // uniform
            float sA = lo_s + (hi_s - lo_s) *
                       ((lo_G - target) / fmaxf(lo_G - hi_G, 1e-30f));
            if (!(sA > lo_s && sA < hi_s)) sA = sB;
            const float t0 = fminf(sA, sB), t1 = fmaxf(sA, sB);

            float a0 = 0.0f, a1 = 0.0f;
            int   k0 = 0,    k1 = 0;
            #pragma unroll
            for (int q = 0; q < 2; ++q) {
                const bool g0 = cv[q] && (cp[q] >= t0);
                const bool g1 = cv[q] && (cp[q] >= t1);
                a0 += g0 ? cp[q] : 0.0f; k0 += (int)__popcll(__ballot(g0));
                a1 += g1 ? cp[q] : 0.0f; k1 += (int)__popcll(__ballot(g1));
            }
            dppSum2(a0, a1);
            if (lane == 0) { xf_c1[it & 1][wid * 2 + 0] = a0;
                             xf_c1[it & 1][wid * 2 + 1] = a1;
                             xi_c1[it & 1][wid * 2 + 0] = k0;
                             xi_c1[it & 1][wid * 2 + 1] = k1; }
            __syncthreads();
            const float M0 = Gh + xf_c1[it & 1][0] + xf_c1[it & 1][2];
            const float M1 = Gh + xf_c1[it & 1][1] + xf_c1[it & 1][3];
            const int   D0 = Ch + xi_c1[it & 1][0] + xi_c1[it & 1][2];
            const int   D1 = Ch + xi_c1[it & 1][1] + xi_c1[it & 1][3];
            if      (M1 >= target) { lo_s = t1; lo_G = M1; lo_C = D1; }
            else if (M0 >= target) { lo_s = t0; lo_G = M0; lo_C = D0;
                                     hi_s = t1; hi_G = M1; hi_C = D1; }
            else                   { hi_s = t0; hi_G = M0; hi_C = D0; }
        }

        // ---- Phase C2: exact distinct-value walk downward from hi_s ----
        float scur = hi_s, M = hi_G;
        bool ok = false;
        pstar = lo_s;
        for (int e = 0; e < 16; ++e) {
            float vl = 0.0f;
            #pragma unroll
            for (int q = 0; q < 2; ++q)
                vl = fmaxf(vl, (cv[q] && cp[q] < scur) ? cp[q] : 0.0f);
            const float vw = dppMax(vl);
            if (lane == 0) xf_c2v[e & 1][wid] = vw;
            __syncthreads();
            const float v = fmaxf(xf_c2v[e & 1][0], xf_c2v[e & 1][1]);
            if (!(v > 0.0f)) break;            // uniform; fp knife-edge
            int cvo = 0;
            #pragma unroll
            for (int q = 0; q < 2; ++q)
                cvo += (int)__popcll(__ballot(cv[q] && (cp[q] == v)));
            if (lane == 0) xi_c2c[e & 1][wid] = cvo;
            __syncthreads();
            const int cvn = xi_c2c[e & 1][0] + xi_c2c[e & 1][1];
            const float Mn = M + v * (float)cvn;  // exact: ties bit-identical
            if (Mn >= target) { pstar = v; mb = M; cnt = cvn; ok = true; break; }
            M = Mn; scur = v;
        }
        haveTie = ok;
        if (!ok) {
            pstar = (lo_s > 0.0f) ? __uint_as_float(__float_as_uint(lo_s) - 1u)
                                  : 0.0f;
        }
    }

    // ---- Phase D: spd = sum_{p > p*} p * (-log p) via select-to-1 ----
    float s0 = 0.0f, s1 = 0.0f;
    #pragma unroll
    for (int k = 0; k < KW; k += 2) {
        const float t0 = (p[k]     > pstar) ? p[k]     : 1.0f;
        const float t1 = (p[k + 1] > pstar) ? p[k + 1] : 1.0f;
        s0 += t0 * (-__logf(t0));
        s1 += t1 * (-__logf(t1));
    }
    const float spdw = dppSum(s0 + s1);
    if (lane == 0) xf_spd[wid] = spdw;
    __syncthreads();

    if (tid == 0) {
        const float spd = xf_spd[0] + xf_spd[1];
        float tie = 0.0f;
        if (haveTie) {
            const float R = (target - mb) / pstar;      // exclusive-csum rule
            int q = (int)ceilf(R);
            if (q < 1) q = 1;
            if (q > cnt) q = cnt;
            tie = (float)q * pstar * (-__logf(pstar));
        }
        const float v = (spd + tie) / Z;
        if (partial) partial[row] = v;       // per-row, no atomic
        else         atomicAdd(out, v);      // ws_size fallback
    }
}

// Deterministic 2nd-stage reduce: n (<=16384) floats -> out[0].
__global__ __launch_bounds__(1024) void apml_reduce(
        const float* __restrict__ partial, float* __restrict__ out, int n) {
    __shared__ float s[16];
    const int t = threadIdx.x;
    float a = 0.0f;
    #pragma unroll
    for (int q = 0; q < 16; ++q) {
        const int i = t * 16 + q;
        a += (i < n) ? partial[i] : 0.0f;
    }
    a = dppSum(a);
    if ((t & 63) == 0) s[t >> 6] = a;
    __syncthreads();
    if (t == 0) {
        float r = 0.0f;
        #pragma unroll
        for (int w = 0; w < 16; ++w) r += s[w];
        out[0] = r;
    }
}

extern "C" void kernel_launch(void* const* d_in, const int* in_sizes, int n_in,
                              void* d_out, int out_size, void* d_ws, size_t ws_size,
                              hipStream_t stream) {
    const float* x = (const float*)d_in[0];   // [B, N, 3]
    const float* y = (const float*)d_in[1];   // [B, M, 3]
    float* out = (float*)d_out;               // scalar

    const int nrows = in_sizes[0] / 3;        // B * N = 16384

    const size_t part_bytes = (size_t)nrows * sizeof(float);

    if (d_ws && ws_size >= part_bytes && nrows <= 16384) {
        float* partial = (float*)d_ws;
        apml_row_pair<<<nrows, 128, 0, stream>>>(x, y, partial, out);
        apml_reduce<<<1, 1024, 0, stream>>>(partial, out, nrows);
    } else {
        hipMemsetAsync(out, 0, sizeof(float), stream);   // capture-legal
        apml_row_pair<<<nrows, 128, 0, stream>>>(x, y, nullptr, out);
    }
}